// Round 11
// baseline (634.418 us; speedup 1.0000x reference)
//
#include <hip/hip_runtime.h>
#include <math.h>

// Problem constants: B=4, H=384, W=1280, NUM=8, IDX_REF=4
static constexpr int B_ = 4;
static constexpr int H_ = 384;
static constexpr int W_ = 1280;
static constexpr int HW_ = H_ * W_;

typedef _Float16 f16x8 __attribute__((ext_vector_type(8)));
typedef float f32x4 __attribute__((ext_vector_type(4)));

// ---------------------------------------------------------------------------
// R11: L3-resident banding. R10's G=4/BH=384 kept a 253 MB x2s stream ~= L3
// capacity, so conv2's writes were evicted before conv3's reads (62 MB FETCH
// / 154 MB WRITE reaching HBM on conv2). BH=128 shrinks the per-band
// intermediate set to x1s 43 + x2s 85 + oa 31 ~= 160 MB < 256 MB Infinity
// Cache -> conv2/conv3/final consume intermediates at L3 latency instead of
// HBM. Kernels are byte-identical to R10 (single-variable A/B).
// Numerics unchanged from R10 (all-f16 A/B, fused guidance, f16 oa).
// ---------------------------------------------------------------------------

// ---------------------------------------------------------------------------
// prep_w (conv2/conv3): A-fragment-layout f16 tiles (single plane):
//   wb[(t*CICH+c)*9+s][row16][k32].
// ---------------------------------------------------------------------------
template <int C_IN, int C_OUT>
__global__ __launch_bounds__(256) void prep_w(const float* __restrict__ w,
                                              unsigned short* __restrict__ wb)
{
  constexpr int CICH = C_IN / 32;
  constexpr int NCOT = (C_OUT + 15) / 16;
  constexpr int NE = NCOT * CICH * 9 * 512;
  int i = blockIdx.x * 256 + threadIdx.x;
  if (i >= NE) return;
  int k   = i & 31;
  int row = (i >> 5) & 15;
  int ts  = i >> 9;
  int s   = ts % 9;
  int tc  = ts / 9;
  int c   = tc % CICH;
  int t   = tc / CICH;
  int co  = t * 16 + row;
  int ci  = c * 32 + k;
  float v = 0.f;
  if (co < C_OUT) v = w[((size_t)co * C_IN + ci) * 9 + s];
  union { _Float16 f; unsigned short u; } ch;
  ch.f = (_Float16)v;
  wb[i] = ch.u;
}

// ---------------------------------------------------------------------------
// prep_w1 (conv1 12->32): chunk = ky*2 + kc; kc=0: k = kx*16 + ci (kx 0,1);
// kc=1: k<16 -> kx=2, ci=k; else zero. ci >= 12 -> zero.
//   wb1[tc*6 + chunk][row16][k32], NE = 2*6*512 (single plane).
// ---------------------------------------------------------------------------
__global__ __launch_bounds__(256) void prep_w1(const float* __restrict__ w,
                                               unsigned short* __restrict__ wb)
{
  constexpr int NE = 2 * 6 * 512;
  int i = blockIdx.x * 256 + threadIdx.x;
  if (i >= NE) return;
  int k    = i & 31;
  int row  = (i >> 5) & 15;
  int ts   = i >> 9;
  int chunk = ts % 6;
  int tc   = ts / 6;
  int ky   = chunk >> 1;
  int kc   = chunk & 1;
  int kx, ci;
  bool valid;
  if (kc == 0) { kx = k >> 4;  ci = k & 15; valid = (ci < 12); }
  else         { kx = 2;       ci = k & 15; valid = (k < 16) && (ci < 12); }
  int co = tc * 16 + row;
  float v = valid ? w[((size_t)co * 12 + ci) * 9 + ky * 3 + kx] : 0.f;
  union { _Float16 f; unsigned short u; } ch;
  ch.f = (_Float16)v;
  wb[i] = ch.u;
}

// ---------------------------------------------------------------------------
// conv1 MFMA (12->32) with guidance fused into the stage.
// LDS [10][36][16 f16] = 11.5 KB; 48 MFMAs/wave.
// ---------------------------------------------------------------------------
__global__ __launch_bounds__(256, 4) void conv1_mfma(
    const float* __restrict__ disp, const float* __restrict__ normal,
    const float* __restrict__ left, const float* __restrict__ right,
    const unsigned short* __restrict__ wb,
    const float* __restrict__ bn_g, const float* __restrict__ bn_b,
    const float* __restrict__ bn_m, const float* __restrict__ bn_v,
    unsigned short* __restrict__ out,   // f16 octet records (x1s)
    int b0, int out_y0, int out_rows)
{
  constexpr int NCOT = 2;
  constexpr int TY  = 8;
  constexpr int HR  = 10;
  constexpr int TXI = 36;

  __shared__ unsigned short smem[HR * TXI * 16];  // 11520 B

  const int tilesX = W_ / 32;
  int bb = blockIdx.x;
  const int txi = bb % tilesX; bb /= tilesX;
  const int tilesY = (out_rows + TY - 1) / TY;
  const int tyi = bb % tilesY;
  const int gi  = bb / tilesY;
  const int b   = b0 + gi;
  const int x0  = txi * 32;
  const int oy0 = out_y0 + tyi * TY;   // global row coords

  const int tid    = threadIdx.x;
  const int w      = tid >> 6;
  const int lane15 = tid & 15;
  const int kgrp   = (tid >> 4) & 3;
  const int aoff   = lane15 * 32 + kgrp * 8;

  f32x4 acc[NCOT][2][2];
#pragma unroll
  for (int i = 0; i < NCOT; i++)
#pragma unroll
    for (int rr = 0; rr < 2; rr++) {
      acc[i][rr][0] = (f32x4){0.f, 0.f, 0.f, 0.f};
      acc[i][rr][1] = (f32x4){0.f, 0.f, 0.f, 0.f};
    }

  // ---- stage: 360 px; compute guidance in-register, pack 16 f16 ----
  for (int it = tid; it < HR * TXI; it += 256) {
    int row = it / TXI;
    int px  = it - row * TXI;
    int gy  = oy0 - 1 + row;
    int gx  = x0 - 2 + px;
    union { _Float16 f[16]; uint4 u[2]; } R;
    R.u[0] = (uint4){0, 0, 0, 0};
    R.u[1] = (uint4){0, 0, 0, 0};
    if (((unsigned)gy < (unsigned)H_) & ((unsigned)gx < (unsigned)W_)) {
      size_t p = (size_t)gy * W_ + gx;
      float d = disp[(size_t)b * HW_ + p];
      float xs = (float)gx - d;
      float x0f = floorf(xs);
      int xi0 = (int)x0f;
      float w1 = xs - x0f;
      int xi1 = xi0 + 1;
      float v0 = (xi0 >= 0 && xi0 < W_) ? 1.f : 0.f;
      float v1 = (xi1 >= 0 && xi1 < W_) ? 1.f : 0.f;
      int xc0 = min(max(xi0, 0), W_ - 1);
      int xc1 = min(max(xi1, 0), W_ - 1);
      float w0f = (1.f - w1) * v0;
      float w1f = w1 * v1;
#pragma unroll
      for (int c = 0; c < 3; c++) {
        const float* rrow = right + (size_t)(b * 3 + c) * HW_ + (size_t)gy * W_;
        float l = left[(size_t)(b * 3 + c) * HW_ + p];
        float n = normal[(size_t)(b * 3 + c) * HW_ + p];
        float r = rrow[gx];
        float warped = w0f * rrow[xc0] + w1f * rrow[xc1];
        R.f[c]     = (_Float16)n;
        R.f[3 + c] = (_Float16)l;
        R.f[6 + c] = (_Float16)r;
        R.f[9 + c] = (_Float16)(warped - l);
      }
    }
    unsigned short* dst = &smem[it * 16];
    *(uint4*)(dst)     = R.u[0];
    *(uint4*)(dst + 8) = R.u[1];
  }
  __syncthreads();

  // ---- K loop: 6 chunks (ky x {kx01, kx2}) ----
  f16x8 ah[NCOT];
#pragma unroll
  for (int tc = 0; tc < NCOT; tc++)
    ah[tc] = *(const f16x8*)(wb + ((size_t)(tc * 6 + 0) * 512 + aoff));
#pragma unroll
  for (int c = 0; c < 6; c++) {
    const int ky = c >> 1, kc = c & 1;
    f16x8 ahn[NCOT];
    if (c < 5) {
#pragma unroll
      for (int tc = 0; tc < NCOT; tc++)
        ahn[tc] = *(const f16x8*)(wb + ((size_t)(tc * 6 + c + 1) * 512 + aoff));
    }
#pragma unroll
    for (int rr = 0; rr < 2; rr++) {
      const int col = (kc ? 3 : 1) + lane15;
      const int e0 = ((2 * w + rr + ky) * TXI + col) * 16 + kgrp * 8;
      f16x8 b0 = *(const f16x8*)&smem[e0];
      f16x8 b1 = *(const f16x8*)&smem[e0 + 256];   // +16 px
#pragma unroll
      for (int tc = 0; tc < NCOT; tc++) {
        acc[tc][rr][0] = __builtin_amdgcn_mfma_f32_16x16x32_f16(
            ah[tc], b0, acc[tc][rr][0], 0, 0, 0);
        acc[tc][rr][1] = __builtin_amdgcn_mfma_f32_16x16x32_f16(
            ah[tc], b1, acc[tc][rr][1], 0, 0, 0);
      }
    }
    if (c < 5) {
#pragma unroll
      for (int tc = 0; tc < NCOT; tc++) ah[tc] = ahn[tc];
    }
  }

  // ---- epilogue: BN+ReLU, f16 octet records ----
#pragma unroll
  for (int rr = 0; rr < 2; rr++) {
    const int orow = oy0 + 2 * w + rr;
    if (orow < out_y0 + out_rows) {
      const int ox = x0 + lane15;
#pragma unroll
      for (int tc = 0; tc < NCOT; tc++) {
        const int o = tc * 2 + (kgrp >> 1);
        const size_t recbase =
            (((size_t)(gi * 4 + o) * out_rows + (orow - out_y0)) * W_ + ox) * 8
            + (kgrp & 1) * 4;
#pragma unroll
        for (int nt = 0; nt < 2; nt++) {
          union { _Float16 f[4]; uint2 u; } Hh;
#pragma unroll
          for (int j = 0; j < 4; j++) {
            const int co = tc * 16 + kgrp * 4 + j;
            float s = bn_g[co] * rsqrtf(bn_v[co] + 1e-5f);
            float v = fmaxf(acc[tc][rr][nt][j] * s + (bn_b[co] - bn_m[co] * s), 0.f);
            Hh.f[j] = (_Float16)v;
          }
          *(uint2*)&out[recbase + (size_t)nt * 128] = Hh.u;
        }
      }
    }
  }
}

// ---------------------------------------------------------------------------
// conv2/conv3 MFMA: plain f16 A and B, single MFMA per product.
// OUTMODE: 0 = f32 planar, 1 = f16 octet records, 2 = f16 planar.
// LDS: 10 x 36 x 36 f16 = 25.9 KB.
// ---------------------------------------------------------------------------
template <int C_IN, int C_OUT, bool BNRELU, int OUTMODE, int MINW>
__global__ __launch_bounds__(256, MINW) void conv3x3_mfma(
    const unsigned short* __restrict__ in, const unsigned short* __restrict__ wb,
    const float* __restrict__ bn_g, const float* __restrict__ bn_b,
    const float* __restrict__ bn_m, const float* __restrict__ bn_v,
    void* __restrict__ out,
    int in_y0, int in_rows, int out_y0, int out_rows)
{
  constexpr int CICH = C_IN / 32;
  constexpr int NCIO = C_IN / 8;
  constexpr int NCOT = (C_OUT + 15) / 16;
  constexpr int TY  = 8;
  constexpr int HR  = 10;
  constexpr int TXI = 36;
  constexpr int PX2 = 18;
  constexpr int PXW = 36;   // 32 f16 + 4 pad per pixel

  __shared__ unsigned short smem[HR * TXI * PXW];  // 25920 B

  const int tilesX = W_ / 32;
  int bb = blockIdx.x;
  const int txi = bb % tilesX; bb /= tilesX;
  const int tilesY = (out_rows + TY - 1) / TY;
  const int tyi = bb % tilesY;
  const int gi  = bb / tilesY;
  const int x0  = txi * 32;
  const int oy0 = out_y0 + tyi * TY;

  const int tid    = threadIdx.x;
  const int w      = tid >> 6;
  const int lane15 = tid & 15;
  const int kgrp   = (tid >> 4) & 3;
  const int aoff   = lane15 * 32 + kgrp * 8;

  f32x4 acc[NCOT][2][2];
#pragma unroll
  for (int i = 0; i < NCOT; i++)
#pragma unroll
    for (int rr = 0; rr < 2; rr++) {
      acc[i][rr][0] = (f32x4){0.f, 0.f, 0.f, 0.f};
      acc[i][rr][1] = (f32x4){0.f, 0.f, 0.f, 0.f};
    }

  for (int cc = 0; cc < CICH; ++cc) {
    if (cc) __syncthreads();
    for (int it = tid; it < 4 * HR * PX2; it += 256) {   // 720 items
      int cib = it / (HR * PX2);
      int pos = it - cib * (HR * PX2);
      int row = pos / PX2;
      int p2  = pos - row * PX2;
      int gy  = oy0 - 1 + row;
      int by  = gy - in_y0;
      int gx  = x0 - 2 + 2 * p2;
      const bool rok = (unsigned)by < (unsigned)in_rows;
      uint4 h0 = {0,0,0,0}, h1 = {0,0,0,0};
      const unsigned short* src =
          in + (((size_t)(gi * NCIO + cc * 4 + cib) * in_rows + by) * W_ + gx) * 8;
      if (rok & ((unsigned)gx < (unsigned)W_))       h0 = *(const uint4*)(src);
      if (rok & ((unsigned)(gx + 1) < (unsigned)W_)) h1 = *(const uint4*)(src + 8);
      int base = (row * TXI + 2 * p2) * PXW + cib * 8;
      *(uint4*)&smem[base]       = h0;
      *(uint4*)&smem[base + PXW] = h1;
    }
    __syncthreads();

#pragma unroll
    for (int s = 0; s < 9; s++) {
      const int ky = s / 3, kx = s - 3 * ky;
      f16x8 ah[NCOT];
#pragma unroll
      for (int tc = 0; tc < NCOT; tc++)
        ah[tc] = *(const f16x8*)(
            wb + ((size_t)((tc * CICH + cc) * 9 + s) * 512 + aoff));
#pragma unroll
      for (int rr = 0; rr < 2; rr++) {
        const int e0 = ((2 * w + rr + ky) * TXI + 1 + lane15 + kx) * PXW + kgrp * 8;
        f16x8 b0 = *(const f16x8*)&smem[e0];
        f16x8 b1 = *(const f16x8*)&smem[e0 + 16 * PXW];
#pragma unroll
        for (int tc = 0; tc < NCOT; tc++) {
          acc[tc][rr][0] = __builtin_amdgcn_mfma_f32_16x16x32_f16(
              ah[tc], b0, acc[tc][rr][0], 0, 0, 0);
          acc[tc][rr][1] = __builtin_amdgcn_mfma_f32_16x16x32_f16(
              ah[tc], b1, acc[tc][rr][1], 0, 0, 0);
        }
      }
    }
  }

#pragma unroll
  for (int rr = 0; rr < 2; rr++) {
    const int orow = oy0 + 2 * w + rr;
    if (orow < out_y0 + out_rows) {
      const int ox = x0 + lane15;
      if constexpr (OUTMODE == 1) {
        unsigned short* outs = (unsigned short*)out;
#pragma unroll
        for (int tc = 0; tc < NCOT; tc++) {
          const int o = tc * 2 + (kgrp >> 1);
          const size_t recbase =
              (((size_t)(gi * (C_OUT / 8) + o) * out_rows + (orow - out_y0)) * W_ + ox) * 8
              + (kgrp & 1) * 4;
#pragma unroll
          for (int nt = 0; nt < 2; nt++) {
            union { _Float16 f[4]; uint2 u; } Hh;
#pragma unroll
            for (int j = 0; j < 4; j++) {
              float v = acc[tc][rr][nt][j];
              if constexpr (BNRELU) {
                const int co = tc * 16 + kgrp * 4 + j;
                float s = bn_g[co] * rsqrtf(bn_v[co] + 1e-5f);
                v = fmaxf(v * s + (bn_b[co] - bn_m[co] * s), 0.f);
              }
              Hh.f[j] = (_Float16)v;
            }
            *(uint2*)&outs[recbase + (size_t)nt * 128] = Hh.u;
          }
        }
      } else if constexpr (OUTMODE == 2) {
        unsigned short* outs = (unsigned short*)out;
#pragma unroll
        for (int tc = 0; tc < NCOT; tc++) {
#pragma unroll
          for (int j = 0; j < 4; j++) {
            const int co = tc * 16 + kgrp * 4 + j;
            if (co < C_OUT) {
              float r0 = acc[tc][rr][0][j];
              float r1 = acc[tc][rr][1][j];
              if constexpr (BNRELU) {
                float sc = bn_g[co] * rsqrtf(bn_v[co] + 1e-5f);
                float of = bn_b[co] - bn_m[co] * sc;
                r0 = fmaxf(r0 * sc + of, 0.f);
                r1 = fmaxf(r1 * sc + of, 0.f);
              }
              unsigned short* bp = outs + ((size_t)(gi * C_OUT + co) * out_rows +
                                           (orow - out_y0)) * (size_t)W_;
              union { _Float16 f; unsigned short u; } c0, c1;
              c0.f = (_Float16)r0; c1.f = (_Float16)r1;
              bp[ox]      = c0.u;
              bp[ox + 16] = c1.u;
            }
          }
        }
      } else {
        float* outf = (float*)out;
#pragma unroll
        for (int tc = 0; tc < NCOT; tc++) {
#pragma unroll
          for (int j = 0; j < 4; j++) {
            const int co = tc * 16 + kgrp * 4 + j;
            if (co < C_OUT) {
              float r0 = acc[tc][rr][0][j];
              float r1 = acc[tc][rr][1][j];
              if constexpr (BNRELU) {
                float sc = bn_g[co] * rsqrtf(bn_v[co] + 1e-5f);
                float of = bn_b[co] - bn_m[co] * sc;
                r0 = fmaxf(r0 * sc + of, 0.f);
                r1 = fmaxf(r1 * sc + of, 0.f);
              }
              float* bp = outf + ((size_t)(gi * C_OUT + co) * out_rows +
                                  (orow - out_y0)) * (size_t)W_;
              bp[ox]      = r0;
              bp[ox + 16] = r1;
            }
          }
        }
      }
    }
  }
}

// ---------------------------------------------------------------------------
// Fused propagation epilogue over a band. oa is f16 planar (24 ch).
// ---------------------------------------------------------------------------
__device__ __forceinline__ float bilin1(const float* __restrict__ img,
                                        float ys, float xs)
{
  float y0f = floorf(ys), x0f = floorf(xs);
  int y0 = (int)y0f, x0 = (int)x0f;
  float wy1 = ys - y0f, wx1 = xs - x0f;
  float wy0 = 1.f - wy1, wx0 = 1.f - wx1;
  int y1 = y0 + 1, x1 = x0 + 1;
  float vy0 = (y0 >= 0 && y0 < H_) ? 1.f : 0.f;
  float vy1 = (y1 >= 0 && y1 < H_) ? 1.f : 0.f;
  float vx0 = (x0 >= 0 && x0 < W_) ? 1.f : 0.f;
  float vx1 = (x1 >= 0 && x1 < W_) ? 1.f : 0.f;
  int yc0 = min(max(y0, 0), H_ - 1), yc1 = min(max(y1, 0), H_ - 1);
  int xc0 = min(max(x0, 0), W_ - 1), xc1 = min(max(x1, 0), W_ - 1);
  const float* r0 = img + (size_t)yc0 * W_;
  const float* r1 = img + (size_t)yc1 * W_;
  float v00 = r0[xc0], v01 = r0[xc1], v10 = r1[xc0], v11 = r1[xc1];
  return (wy0 * vy0) * ((wx0 * vx0) * v00 + (wx1 * vx1) * v01) +
         (wy1 * vy1) * ((wx0 * vx0) * v10 + (wx1 * vx1) * v11);
}

__global__ __launch_bounds__(256) void final_band(
    const unsigned short* __restrict__ oa, const float* __restrict__ conf,
    const float* __restrict__ disp, const float* __restrict__ asc,
    float* __restrict__ out, int b0, int g, int y0g, int rows)
{
  int idx = blockIdx.x * 256 + threadIdx.x;
  if (idx >= g * rows * W_) return;
  int x = idx % W_;
  int t = idx / W_;
  int yr = t % rows;
  int gi = t / rows;
  int y = y0g + yr;
  int b = b0 + gi;
  int p = y * W_ + x;

  const float scale = 1.f / (asc[0] + 1e-8f);
  const float* cimg = conf + (size_t)b * HW_;
  const float* dimg = disp + (size_t)b * HW_;
  const unsigned short* oab = oa + (size_t)gi * 24 * rows * W_;
  const size_t cs = (size_t)rows * W_;
  const size_t q = (size_t)yr * W_ + x;

  float offy[8], offx[8], a[8];
#pragma unroll
  for (int k = 0; k < 8; k++) {
    offy[k] = (float)(*(const _Float16*)&oab[(size_t)k * cs + q]);
    offx[k] = (float)(*(const _Float16*)&oab[(size_t)(8 + k) * cs + q]);
    float ar = (float)(*(const _Float16*)&oab[(size_t)(16 + k) * cs + q]);
    float ca = bilin1(cimg, (float)y + offy[k], (float)x + offx[k]);
    a[k] = tanhf(ar) * scale * ca;
  }

  float s = 1e-4f;
#pragma unroll
  for (int k = 0; k < 8; k++) s += fabsf(a[k]);
  s = fmaxf(s, 1.f);
  float inv = 1.f / s;
  float suma = 0.f;
#pragma unroll
  for (int k = 0; k < 8; k++) { a[k] *= inv; suma += a[k]; }
  float aref = 1.f - suma;

  float inter = 0.f;
#pragma unroll
  for (int k9 = 0; k9 < 9; k9++) {
    float oy, ox, w;
    if (k9 < 4)       { oy = offy[k9];     ox = offx[k9];     w = a[k9]; }
    else if (k9 == 4) { oy = 0.f;          ox = 0.f;          w = aref;  }
    else              { oy = offy[k9 - 1]; ox = offx[k9 - 1]; w = a[k9 - 1]; }
    float ky = (float)(k9 / 3) - 1.f;
    float kx = (float)(k9 % 3) - 1.f;
    inter += w * bilin1(dimg, (float)y + ky + oy, (float)x + kx + ox);
  }
  inter = fmaxf(inter, 0.f);
  float cd = dimg[p];
  out[(size_t)b * HW_ + p] = fmaxf(0.7f * cd + 0.3f * inter, 0.f);
}

// ---------------------------------------------------------------------------
extern "C" void kernel_launch(void* const* d_in, const int* in_sizes, int n_in,
                              void* d_out, int out_size, void* d_ws, size_t ws_size,
                              hipStream_t stream)
{
  const float* disp   = (const float*)d_in[0];
  const float* normal = (const float*)d_in[1];
  const float* left   = (const float*)d_in[2];
  const float* right  = (const float*)d_in[3];
  const float* conf   = (const float*)d_in[4];
  const float* w1     = (const float*)d_in[5];
  const float* g1     = (const float*)d_in[6];
  const float* b1     = (const float*)d_in[7];
  const float* m1     = (const float*)d_in[8];
  const float* v1     = (const float*)d_in[9];
  const float* w2     = (const float*)d_in[10];
  const float* g2     = (const float*)d_in[11];
  const float* b2     = (const float*)d_in[12];
  const float* m2     = (const float*)d_in[13];
  const float* v2     = (const float*)d_in[14];
  const float* w3     = (const float*)d_in[15];
  const float* asc    = (const float*)d_in[16];
  float* out = (float*)d_out;

  constexpr int WB1E = 2 * 6 * 512;      // 6144 ushorts (single plane)
  constexpr int WB2E = 4 * 1 * 9 * 512;  // 18432
  constexpr int WB3E = 2 * 2 * 9 * 512;  // 18432
  const size_t wbytes = (size_t)(WB1E + WB2E + WB3E) * sizeof(unsigned short);

  // Band buffers (bytes/px-col): x1s 64*(bh+4), x2s 128*(bh+2).
  // oa (24ch f16 = 48 B) aliases ws start; 48*bh <= 64*(bh+4).
  // R11: prefer BH=128 so per-band x1s+x2s+oa ~= 160 MB fits the 256 MB L3.
  struct Cfg { int g, bh; };
  const Cfg cfgs[] = {{4, 128}, {4, 192}, {4, 384}, {2, 384}, {1, 384},
                      {4, 96}, {2, 96}, {1, 96}, {1, 48}, {1, 24},
                      {1, 12}, {1, 8}, {1, 4}};
  int G = 1, BH = 4;
  for (const Cfg& c : cfgs) {
    size_t bytes = (size_t)c.g * W_ *
                   (64u * (c.bh + 4) + 128u * (c.bh + 2));
    if (bytes + wbytes <= ws_size) { G = c.g; BH = c.bh; break; }
  }

  unsigned short* x1s = (unsigned short*)d_ws;
  unsigned short* x2s = x1s + (size_t)G * 32 * (BH + 4) * W_;
  unsigned short* oa_buf = (unsigned short*)d_ws;  // alias: x1s dead by conv3
  unsigned short* wb1 = x2s + (size_t)G * 64 * (BH + 2) * W_;
  unsigned short* wb2 = wb1 + WB1E;
  unsigned short* wb3 = wb2 + WB2E;

  prep_w1<<<(WB1E + 255) / 256, 256, 0, stream>>>(w1, wb1);
  prep_w<32, 64><<<(WB2E + 255) / 256, 256, 0, stream>>>(w2, wb2);
  prep_w<64, 24><<<(WB3E + 255) / 256, 256, 0, stream>>>(w3, wb3);

  const int tilesX = W_ / 32;

  for (int b0 = 0; b0 < B_; b0 += G) {
    for (int y0 = 0; y0 < H_; y0 += BH) {
      const int rows_out = min(BH, H_ - y0);
      const int y_x2_0 = max(y0 - 1, 0);
      const int y_x2_1 = min(y0 + rows_out + 1, H_);
      const int rows_x2 = y_x2_1 - y_x2_0;
      const int y_x1_0 = max(y0 - 2, 0);
      const int y_x1_1 = min(y0 + rows_out + 2, H_);
      const int rows_x1 = y_x1_1 - y_x1_0;

      {
        // conv1 12 -> 32 (MFMA, guidance fused, f16 out)
        int grid = tilesX * ((rows_x1 + 7) / 8) * G;
        conv1_mfma<<<grid, 256, 0, stream>>>(
            disp, normal, left, right, wb1, g1, b1, m1, v1, x1s,
            b0, y_x1_0, rows_x1);
      }
      {
        // conv2 32 -> 64 (MFMA f16, f16 octet in/out)
        int grid = tilesX * ((rows_x2 + 7) / 8) * G;
        conv3x3_mfma<32, 64, true, 1, 4><<<grid, 256, 0, stream>>>(
            x1s, wb2, g2, b2, m2, v2, (void*)x2s,
            y_x1_0, rows_x1, y_x2_0, rows_x2);
      }
      {
        // conv3 64 -> 24 (MFMA f16, f16 octet in, f16 planar out)
        int grid = tilesX * ((rows_out + 7) / 8) * G;
        conv3x3_mfma<64, 24, false, 2, 4><<<grid, 256, 0, stream>>>(
            x2s, wb3, nullptr, nullptr, nullptr, nullptr, (void*)oa_buf,
            y_x2_0, rows_x2, y0, rows_out);
      }
      {
        int n = G * rows_out * W_;
        final_band<<<(n + 255) / 256, 256, 0, stream>>>(
            oa_buf, conf, disp, asc, out, b0, G, y0, rows_out);
      }
    }
  }
}

// Round 12
// 575.435 us; speedup vs baseline: 1.1025x; 1.1025x over previous
//
#include <hip/hip_runtime.h>
#include <math.h>

// Problem constants: B=4, H=384, W=1280, NUM=8, IDX_REF=4
static constexpr int B_ = 4;
static constexpr int H_ = 384;
static constexpr int W_ = 1280;
static constexpr int HW_ = H_ * W_;

typedef _Float16 f16x8 __attribute__((ext_vector_type(8)));
typedef float f32x4 __attribute__((ext_vector_type(4)));

// ---------------------------------------------------------------------------
// R12: revert R11's banding (BH=128 RAISED total FETCH 62->127 MB and lost
// per-dispatch efficiency -> L3 was already doing what it could at BH=384).
// Restore the one-tap-ahead A-fragment prefetch in conv3x3_mfma (dropped in
// R9): each tap otherwise starts with NCOT L2 loads (~200 cyc) feeding MFMAs
// immediately — a per-tap serial bubble vs 256 MFMA cyc/tap.
// Numerics unchanged from R10 (all-f16 A/B, fused guidance, f16 oa).
// ---------------------------------------------------------------------------

// ---------------------------------------------------------------------------
// prep_w (conv2/conv3): A-fragment-layout f16 tiles (single plane):
//   wb[(t*CICH+c)*9+s][row16][k32].
// ---------------------------------------------------------------------------
template <int C_IN, int C_OUT>
__global__ __launch_bounds__(256) void prep_w(const float* __restrict__ w,
                                              unsigned short* __restrict__ wb)
{
  constexpr int CICH = C_IN / 32;
  constexpr int NCOT = (C_OUT + 15) / 16;
  constexpr int NE = NCOT * CICH * 9 * 512;
  int i = blockIdx.x * 256 + threadIdx.x;
  if (i >= NE) return;
  int k   = i & 31;
  int row = (i >> 5) & 15;
  int ts  = i >> 9;
  int s   = ts % 9;
  int tc  = ts / 9;
  int c   = tc % CICH;
  int t   = tc / CICH;
  int co  = t * 16 + row;
  int ci  = c * 32 + k;
  float v = 0.f;
  if (co < C_OUT) v = w[((size_t)co * C_IN + ci) * 9 + s];
  union { _Float16 f; unsigned short u; } ch;
  ch.f = (_Float16)v;
  wb[i] = ch.u;
}

// ---------------------------------------------------------------------------
// prep_w1 (conv1 12->32): chunk = ky*2 + kc; kc=0: k = kx*16 + ci (kx 0,1);
// kc=1: k<16 -> kx=2, ci=k; else zero. ci >= 12 -> zero.
//   wb1[tc*6 + chunk][row16][k32], NE = 2*6*512 (single plane).
// ---------------------------------------------------------------------------
__global__ __launch_bounds__(256) void prep_w1(const float* __restrict__ w,
                                               unsigned short* __restrict__ wb)
{
  constexpr int NE = 2 * 6 * 512;
  int i = blockIdx.x * 256 + threadIdx.x;
  if (i >= NE) return;
  int k    = i & 31;
  int row  = (i >> 5) & 15;
  int ts   = i >> 9;
  int chunk = ts % 6;
  int tc   = ts / 6;
  int ky   = chunk >> 1;
  int kc   = chunk & 1;
  int kx, ci;
  bool valid;
  if (kc == 0) { kx = k >> 4;  ci = k & 15; valid = (ci < 12); }
  else         { kx = 2;       ci = k & 15; valid = (k < 16) && (ci < 12); }
  int co = tc * 16 + row;
  float v = valid ? w[((size_t)co * 12 + ci) * 9 + ky * 3 + kx] : 0.f;
  union { _Float16 f; unsigned short u; } ch;
  ch.f = (_Float16)v;
  wb[i] = ch.u;
}

// ---------------------------------------------------------------------------
// conv1 MFMA (12->32) with guidance fused into the stage.
// LDS [10][36][16 f16] = 11.5 KB; 48 MFMAs/wave.
// ---------------------------------------------------------------------------
__global__ __launch_bounds__(256, 4) void conv1_mfma(
    const float* __restrict__ disp, const float* __restrict__ normal,
    const float* __restrict__ left, const float* __restrict__ right,
    const unsigned short* __restrict__ wb,
    const float* __restrict__ bn_g, const float* __restrict__ bn_b,
    const float* __restrict__ bn_m, const float* __restrict__ bn_v,
    unsigned short* __restrict__ out,   // f16 octet records (x1s)
    int b0, int out_y0, int out_rows)
{
  constexpr int NCOT = 2;
  constexpr int TY  = 8;
  constexpr int HR  = 10;
  constexpr int TXI = 36;

  __shared__ unsigned short smem[HR * TXI * 16];  // 11520 B

  const int tilesX = W_ / 32;
  int bb = blockIdx.x;
  const int txi = bb % tilesX; bb /= tilesX;
  const int tilesY = (out_rows + TY - 1) / TY;
  const int tyi = bb % tilesY;
  const int gi  = bb / tilesY;
  const int b   = b0 + gi;
  const int x0  = txi * 32;
  const int oy0 = out_y0 + tyi * TY;   // global row coords

  const int tid    = threadIdx.x;
  const int w      = tid >> 6;
  const int lane15 = tid & 15;
  const int kgrp   = (tid >> 4) & 3;
  const int aoff   = lane15 * 32 + kgrp * 8;

  f32x4 acc[NCOT][2][2];
#pragma unroll
  for (int i = 0; i < NCOT; i++)
#pragma unroll
    for (int rr = 0; rr < 2; rr++) {
      acc[i][rr][0] = (f32x4){0.f, 0.f, 0.f, 0.f};
      acc[i][rr][1] = (f32x4){0.f, 0.f, 0.f, 0.f};
    }

  // ---- stage: 360 px; compute guidance in-register, pack 16 f16 ----
  for (int it = tid; it < HR * TXI; it += 256) {
    int row = it / TXI;
    int px  = it - row * TXI;
    int gy  = oy0 - 1 + row;
    int gx  = x0 - 2 + px;
    union { _Float16 f[16]; uint4 u[2]; } R;
    R.u[0] = (uint4){0, 0, 0, 0};
    R.u[1] = (uint4){0, 0, 0, 0};
    if (((unsigned)gy < (unsigned)H_) & ((unsigned)gx < (unsigned)W_)) {
      size_t p = (size_t)gy * W_ + gx;
      float d = disp[(size_t)b * HW_ + p];
      float xs = (float)gx - d;
      float x0f = floorf(xs);
      int xi0 = (int)x0f;
      float w1 = xs - x0f;
      int xi1 = xi0 + 1;
      float v0 = (xi0 >= 0 && xi0 < W_) ? 1.f : 0.f;
      float v1 = (xi1 >= 0 && xi1 < W_) ? 1.f : 0.f;
      int xc0 = min(max(xi0, 0), W_ - 1);
      int xc1 = min(max(xi1, 0), W_ - 1);
      float w0f = (1.f - w1) * v0;
      float w1f = w1 * v1;
#pragma unroll
      for (int c = 0; c < 3; c++) {
        const float* rrow = right + (size_t)(b * 3 + c) * HW_ + (size_t)gy * W_;
        float l = left[(size_t)(b * 3 + c) * HW_ + p];
        float n = normal[(size_t)(b * 3 + c) * HW_ + p];
        float r = rrow[gx];
        float warped = w0f * rrow[xc0] + w1f * rrow[xc1];
        R.f[c]     = (_Float16)n;
        R.f[3 + c] = (_Float16)l;
        R.f[6 + c] = (_Float16)r;
        R.f[9 + c] = (_Float16)(warped - l);
      }
    }
    unsigned short* dst = &smem[it * 16];
    *(uint4*)(dst)     = R.u[0];
    *(uint4*)(dst + 8) = R.u[1];
  }
  __syncthreads();

  // ---- K loop: 6 chunks (ky x {kx01, kx2}), A prefetched one chunk ahead ----
  f16x8 ah[NCOT];
#pragma unroll
  for (int tc = 0; tc < NCOT; tc++)
    ah[tc] = *(const f16x8*)(wb + ((size_t)(tc * 6 + 0) * 512 + aoff));
#pragma unroll
  for (int c = 0; c < 6; c++) {
    const int ky = c >> 1, kc = c & 1;
    f16x8 ahn[NCOT];
    if (c < 5) {
#pragma unroll
      for (int tc = 0; tc < NCOT; tc++)
        ahn[tc] = *(const f16x8*)(wb + ((size_t)(tc * 6 + c + 1) * 512 + aoff));
    }
#pragma unroll
    for (int rr = 0; rr < 2; rr++) {
      const int col = (kc ? 3 : 1) + lane15;
      const int e0 = ((2 * w + rr + ky) * TXI + col) * 16 + kgrp * 8;
      f16x8 b0 = *(const f16x8*)&smem[e0];
      f16x8 b1 = *(const f16x8*)&smem[e0 + 256];   // +16 px
#pragma unroll
      for (int tc = 0; tc < NCOT; tc++) {
        acc[tc][rr][0] = __builtin_amdgcn_mfma_f32_16x16x32_f16(
            ah[tc], b0, acc[tc][rr][0], 0, 0, 0);
        acc[tc][rr][1] = __builtin_amdgcn_mfma_f32_16x16x32_f16(
            ah[tc], b1, acc[tc][rr][1], 0, 0, 0);
      }
    }
    if (c < 5) {
#pragma unroll
      for (int tc = 0; tc < NCOT; tc++) ah[tc] = ahn[tc];
    }
  }

  // ---- epilogue: BN+ReLU, f16 octet records ----
#pragma unroll
  for (int rr = 0; rr < 2; rr++) {
    const int orow = oy0 + 2 * w + rr;
    if (orow < out_y0 + out_rows) {
      const int ox = x0 + lane15;
#pragma unroll
      for (int tc = 0; tc < NCOT; tc++) {
        const int o = tc * 2 + (kgrp >> 1);
        const size_t recbase =
            (((size_t)(gi * 4 + o) * out_rows + (orow - out_y0)) * W_ + ox) * 8
            + (kgrp & 1) * 4;
#pragma unroll
        for (int nt = 0; nt < 2; nt++) {
          union { _Float16 f[4]; uint2 u; } Hh;
#pragma unroll
          for (int j = 0; j < 4; j++) {
            const int co = tc * 16 + kgrp * 4 + j;
            float s = bn_g[co] * rsqrtf(bn_v[co] + 1e-5f);
            float v = fmaxf(acc[tc][rr][nt][j] * s + (bn_b[co] - bn_m[co] * s), 0.f);
            Hh.f[j] = (_Float16)v;
          }
          *(uint2*)&out[recbase + (size_t)nt * 128] = Hh.u;
        }
      }
    }
  }
}

// ---------------------------------------------------------------------------
// conv2/conv3 MFMA: plain f16 A and B, single MFMA per product.
// R12: A-fragment prefetch one tap ahead (R9 dropped it; per-tap L2 latency
// was serial with the MFMAs). OUTMODE: 0 = f32 planar, 1 = f16 octet records,
// 2 = f16 planar. LDS: 10 x 36 x 36 f16 = 25.9 KB.
// ---------------------------------------------------------------------------
template <int C_IN, int C_OUT, bool BNRELU, int OUTMODE, int MINW>
__global__ __launch_bounds__(256, MINW) void conv3x3_mfma(
    const unsigned short* __restrict__ in, const unsigned short* __restrict__ wb,
    const float* __restrict__ bn_g, const float* __restrict__ bn_b,
    const float* __restrict__ bn_m, const float* __restrict__ bn_v,
    void* __restrict__ out,
    int in_y0, int in_rows, int out_y0, int out_rows)
{
  constexpr int CICH = C_IN / 32;
  constexpr int NCIO = C_IN / 8;
  constexpr int NCOT = (C_OUT + 15) / 16;
  constexpr int TY  = 8;
  constexpr int HR  = 10;
  constexpr int TXI = 36;
  constexpr int PX2 = 18;
  constexpr int PXW = 36;   // 32 f16 + 4 pad per pixel

  __shared__ unsigned short smem[HR * TXI * PXW];  // 25920 B

  const int tilesX = W_ / 32;
  int bb = blockIdx.x;
  const int txi = bb % tilesX; bb /= tilesX;
  const int tilesY = (out_rows + TY - 1) / TY;
  const int tyi = bb % tilesY;
  const int gi  = bb / tilesY;
  const int x0  = txi * 32;
  const int oy0 = out_y0 + tyi * TY;

  const int tid    = threadIdx.x;
  const int w      = tid >> 6;
  const int lane15 = tid & 15;
  const int kgrp   = (tid >> 4) & 3;
  const int aoff   = lane15 * 32 + kgrp * 8;

  f32x4 acc[NCOT][2][2];
#pragma unroll
  for (int i = 0; i < NCOT; i++)
#pragma unroll
    for (int rr = 0; rr < 2; rr++) {
      acc[i][rr][0] = (f32x4){0.f, 0.f, 0.f, 0.f};
      acc[i][rr][1] = (f32x4){0.f, 0.f, 0.f, 0.f};
    }

  for (int cc = 0; cc < CICH; ++cc) {
    if (cc) __syncthreads();
    for (int it = tid; it < 4 * HR * PX2; it += 256) {   // 720 items
      int cib = it / (HR * PX2);
      int pos = it - cib * (HR * PX2);
      int row = pos / PX2;
      int p2  = pos - row * PX2;
      int gy  = oy0 - 1 + row;
      int by  = gy - in_y0;
      int gx  = x0 - 2 + 2 * p2;
      const bool rok = (unsigned)by < (unsigned)in_rows;
      uint4 h0 = {0,0,0,0}, h1 = {0,0,0,0};
      const unsigned short* src =
          in + (((size_t)(gi * NCIO + cc * 4 + cib) * in_rows + by) * W_ + gx) * 8;
      if (rok & ((unsigned)gx < (unsigned)W_))       h0 = *(const uint4*)(src);
      if (rok & ((unsigned)(gx + 1) < (unsigned)W_)) h1 = *(const uint4*)(src + 8);
      int base = (row * TXI + 2 * p2) * PXW + cib * 8;
      *(uint4*)&smem[base]       = h0;
      *(uint4*)&smem[base + PXW] = h1;
    }
    __syncthreads();

    // ---- K loop: 9 taps; A prefetched one tap ahead ----
    f16x8 ah[NCOT];
#pragma unroll
    for (int tc = 0; tc < NCOT; tc++)
      ah[tc] = *(const f16x8*)(
          wb + ((size_t)((tc * CICH + cc) * 9 + 0) * 512 + aoff));
#pragma unroll
    for (int s = 0; s < 9; s++) {
      const int ky = s / 3, kx = s - 3 * ky;
      f16x8 ahn[NCOT];
      if (s < 8) {
#pragma unroll
        for (int tc = 0; tc < NCOT; tc++)
          ahn[tc] = *(const f16x8*)(
              wb + ((size_t)((tc * CICH + cc) * 9 + s + 1) * 512 + aoff));
      }
#pragma unroll
      for (int rr = 0; rr < 2; rr++) {
        const int e0 = ((2 * w + rr + ky) * TXI + 1 + lane15 + kx) * PXW + kgrp * 8;
        f16x8 b0 = *(const f16x8*)&smem[e0];
        f16x8 b1 = *(const f16x8*)&smem[e0 + 16 * PXW];
#pragma unroll
        for (int tc = 0; tc < NCOT; tc++) {
          acc[tc][rr][0] = __builtin_amdgcn_mfma_f32_16x16x32_f16(
              ah[tc], b0, acc[tc][rr][0], 0, 0, 0);
          acc[tc][rr][1] = __builtin_amdgcn_mfma_f32_16x16x32_f16(
              ah[tc], b1, acc[tc][rr][1], 0, 0, 0);
        }
      }
      if (s < 8) {
#pragma unroll
        for (int tc = 0; tc < NCOT; tc++) ah[tc] = ahn[tc];
      }
    }
  }

#pragma unroll
  for (int rr = 0; rr < 2; rr++) {
    const int orow = oy0 + 2 * w + rr;
    if (orow < out_y0 + out_rows) {
      const int ox = x0 + lane15;
      if constexpr (OUTMODE == 1) {
        unsigned short* outs = (unsigned short*)out;
#pragma unroll
        for (int tc = 0; tc < NCOT; tc++) {
          const int o = tc * 2 + (kgrp >> 1);
          const size_t recbase =
              (((size_t)(gi * (C_OUT / 8) + o) * out_rows + (orow - out_y0)) * W_ + ox) * 8
              + (kgrp & 1) * 4;
#pragma unroll
          for (int nt = 0; nt < 2; nt++) {
            union { _Float16 f[4]; uint2 u; } Hh;
#pragma unroll
            for (int j = 0; j < 4; j++) {
              float v = acc[tc][rr][nt][j];
              if constexpr (BNRELU) {
                const int co = tc * 16 + kgrp * 4 + j;
                float s = bn_g[co] * rsqrtf(bn_v[co] + 1e-5f);
                v = fmaxf(v * s + (bn_b[co] - bn_m[co] * s), 0.f);
              }
              Hh.f[j] = (_Float16)v;
            }
            *(uint2*)&outs[recbase + (size_t)nt * 128] = Hh.u;
          }
        }
      } else if constexpr (OUTMODE == 2) {
        unsigned short* outs = (unsigned short*)out;
#pragma unroll
        for (int tc = 0; tc < NCOT; tc++) {
#pragma unroll
          for (int j = 0; j < 4; j++) {
            const int co = tc * 16 + kgrp * 4 + j;
            if (co < C_OUT) {
              float r0 = acc[tc][rr][0][j];
              float r1 = acc[tc][rr][1][j];
              if constexpr (BNRELU) {
                float sc = bn_g[co] * rsqrtf(bn_v[co] + 1e-5f);
                float of = bn_b[co] - bn_m[co] * sc;
                r0 = fmaxf(r0 * sc + of, 0.f);
                r1 = fmaxf(r1 * sc + of, 0.f);
              }
              unsigned short* bp = outs + ((size_t)(gi * C_OUT + co) * out_rows +
                                           (orow - out_y0)) * (size_t)W_;
              union { _Float16 f; unsigned short u; } c0, c1;
              c0.f = (_Float16)r0; c1.f = (_Float16)r1;
              bp[ox]      = c0.u;
              bp[ox + 16] = c1.u;
            }
          }
        }
      } else {
        float* outf = (float*)out;
#pragma unroll
        for (int tc = 0; tc < NCOT; tc++) {
#pragma unroll
          for (int j = 0; j < 4; j++) {
            const int co = tc * 16 + kgrp * 4 + j;
            if (co < C_OUT) {
              float r0 = acc[tc][rr][0][j];
              float r1 = acc[tc][rr][1][j];
              if constexpr (BNRELU) {
                float sc = bn_g[co] * rsqrtf(bn_v[co] + 1e-5f);
                float of = bn_b[co] - bn_m[co] * sc;
                r0 = fmaxf(r0 * sc + of, 0.f);
                r1 = fmaxf(r1 * sc + of, 0.f);
              }
              float* bp = outf + ((size_t)(gi * C_OUT + co) * out_rows +
                                  (orow - out_y0)) * (size_t)W_;
              bp[ox]      = r0;
              bp[ox + 16] = r1;
            }
          }
        }
      }
    }
  }
}

// ---------------------------------------------------------------------------
// Fused propagation epilogue over a band. oa is f16 planar (24 ch).
// ---------------------------------------------------------------------------
__device__ __forceinline__ float bilin1(const float* __restrict__ img,
                                        float ys, float xs)
{
  float y0f = floorf(ys), x0f = floorf(xs);
  int y0 = (int)y0f, x0 = (int)x0f;
  float wy1 = ys - y0f, wx1 = xs - x0f;
  float wy0 = 1.f - wy1, wx0 = 1.f - wx1;
  int y1 = y0 + 1, x1 = x0 + 1;
  float vy0 = (y0 >= 0 && y0 < H_) ? 1.f : 0.f;
  float vy1 = (y1 >= 0 && y1 < H_) ? 1.f : 0.f;
  float vx0 = (x0 >= 0 && x0 < W_) ? 1.f : 0.f;
  float vx1 = (x1 >= 0 && x1 < W_) ? 1.f : 0.f;
  int yc0 = min(max(y0, 0), H_ - 1), yc1 = min(max(y1, 0), H_ - 1);
  int xc0 = min(max(x0, 0), W_ - 1), xc1 = min(max(x1, 0), W_ - 1);
  const float* r0 = img + (size_t)yc0 * W_;
  const float* r1 = img + (size_t)yc1 * W_;
  float v00 = r0[xc0], v01 = r0[xc1], v10 = r1[xc0], v11 = r1[xc1];
  return (wy0 * vy0) * ((wx0 * vx0) * v00 + (wx1 * vx1) * v01) +
         (wy1 * vy1) * ((wx0 * vx0) * v10 + (wx1 * vx1) * v11);
}

__global__ __launch_bounds__(256) void final_band(
    const unsigned short* __restrict__ oa, const float* __restrict__ conf,
    const float* __restrict__ disp, const float* __restrict__ asc,
    float* __restrict__ out, int b0, int g, int y0g, int rows)
{
  int idx = blockIdx.x * 256 + threadIdx.x;
  if (idx >= g * rows * W_) return;
  int x = idx % W_;
  int t = idx / W_;
  int yr = t % rows;
  int gi = t / rows;
  int y = y0g + yr;
  int b = b0 + gi;
  int p = y * W_ + x;

  const float scale = 1.f / (asc[0] + 1e-8f);
  const float* cimg = conf + (size_t)b * HW_;
  const float* dimg = disp + (size_t)b * HW_;
  const unsigned short* oab = oa + (size_t)gi * 24 * rows * W_;
  const size_t cs = (size_t)rows * W_;
  const size_t q = (size_t)yr * W_ + x;

  float offy[8], offx[8], a[8];
#pragma unroll
  for (int k = 0; k < 8; k++) {
    offy[k] = (float)(*(const _Float16*)&oab[(size_t)k * cs + q]);
    offx[k] = (float)(*(const _Float16*)&oab[(size_t)(8 + k) * cs + q]);
    float ar = (float)(*(const _Float16*)&oab[(size_t)(16 + k) * cs + q]);
    float ca = bilin1(cimg, (float)y + offy[k], (float)x + offx[k]);
    a[k] = tanhf(ar) * scale * ca;
  }

  float s = 1e-4f;
#pragma unroll
  for (int k = 0; k < 8; k++) s += fabsf(a[k]);
  s = fmaxf(s, 1.f);
  float inv = 1.f / s;
  float suma = 0.f;
#pragma unroll
  for (int k = 0; k < 8; k++) { a[k] *= inv; suma += a[k]; }
  float aref = 1.f - suma;

  float inter = 0.f;
#pragma unroll
  for (int k9 = 0; k9 < 9; k9++) {
    float oy, ox, w;
    if (k9 < 4)       { oy = offy[k9];     ox = offx[k9];     w = a[k9]; }
    else if (k9 == 4) { oy = 0.f;          ox = 0.f;          w = aref;  }
    else              { oy = offy[k9 - 1]; ox = offx[k9 - 1]; w = a[k9 - 1]; }
    float ky = (float)(k9 / 3) - 1.f;
    float kx = (float)(k9 % 3) - 1.f;
    inter += w * bilin1(dimg, (float)y + ky + oy, (float)x + kx + ox);
  }
  inter = fmaxf(inter, 0.f);
  float cd = dimg[p];
  out[(size_t)b * HW_ + p] = fmaxf(0.7f * cd + 0.3f * inter, 0.f);
}

// ---------------------------------------------------------------------------
extern "C" void kernel_launch(void* const* d_in, const int* in_sizes, int n_in,
                              void* d_out, int out_size, void* d_ws, size_t ws_size,
                              hipStream_t stream)
{
  const float* disp   = (const float*)d_in[0];
  const float* normal = (const float*)d_in[1];
  const float* left   = (const float*)d_in[2];
  const float* right  = (const float*)d_in[3];
  const float* conf   = (const float*)d_in[4];
  const float* w1     = (const float*)d_in[5];
  const float* g1     = (const float*)d_in[6];
  const float* b1     = (const float*)d_in[7];
  const float* m1     = (const float*)d_in[8];
  const float* v1     = (const float*)d_in[9];
  const float* w2     = (const float*)d_in[10];
  const float* g2     = (const float*)d_in[11];
  const float* b2     = (const float*)d_in[12];
  const float* m2     = (const float*)d_in[13];
  const float* v2     = (const float*)d_in[14];
  const float* w3     = (const float*)d_in[15];
  const float* asc    = (const float*)d_in[16];
  float* out = (float*)d_out;

  constexpr int WB1E = 2 * 6 * 512;      // 6144 ushorts (single plane)
  constexpr int WB2E = 4 * 1 * 9 * 512;  // 18432
  constexpr int WB3E = 2 * 2 * 9 * 512;  // 18432
  const size_t wbytes = (size_t)(WB1E + WB2E + WB3E) * sizeof(unsigned short);

  // Band buffers (bytes/px-col): x1s 64*(bh+4), x2s 128*(bh+2).
  // oa (24ch f16 = 48 B) aliases ws start; 48*bh <= 64*(bh+4).
  // R12: BH=384 preferred (R11's BH=128 raised total FETCH and regressed).
  struct Cfg { int g, bh; };
  const Cfg cfgs[] = {{4, 384}, {2, 384}, {1, 384}, {4, 96}, {2, 96},
                      {1, 96}, {1, 48}, {1, 24}, {1, 12}, {1, 8}, {1, 4}};
  int G = 1, BH = 4;
  for (const Cfg& c : cfgs) {
    size_t bytes = (size_t)c.g * W_ *
                   (64u * (c.bh + 4) + 128u * (c.bh + 2));
    if (bytes + wbytes <= ws_size) { G = c.g; BH = c.bh; break; }
  }

  unsigned short* x1s = (unsigned short*)d_ws;
  unsigned short* x2s = x1s + (size_t)G * 32 * (BH + 4) * W_;
  unsigned short* oa_buf = (unsigned short*)d_ws;  // alias: x1s dead by conv3
  unsigned short* wb1 = x2s + (size_t)G * 64 * (BH + 2) * W_;
  unsigned short* wb2 = wb1 + WB1E;
  unsigned short* wb3 = wb2 + WB2E;

  prep_w1<<<(WB1E + 255) / 256, 256, 0, stream>>>(w1, wb1);
  prep_w<32, 64><<<(WB2E + 255) / 256, 256, 0, stream>>>(w2, wb2);
  prep_w<64, 24><<<(WB3E + 255) / 256, 256, 0, stream>>>(w3, wb3);

  const int tilesX = W_ / 32;

  for (int b0 = 0; b0 < B_; b0 += G) {
    for (int y0 = 0; y0 < H_; y0 += BH) {
      const int rows_out = min(BH, H_ - y0);
      const int y_x2_0 = max(y0 - 1, 0);
      const int y_x2_1 = min(y0 + rows_out + 1, H_);
      const int rows_x2 = y_x2_1 - y_x2_0;
      const int y_x1_0 = max(y0 - 2, 0);
      const int y_x1_1 = min(y0 + rows_out + 2, H_);
      const int rows_x1 = y_x1_1 - y_x1_0;

      {
        // conv1 12 -> 32 (MFMA, guidance fused, f16 out)
        int grid = tilesX * ((rows_x1 + 7) / 8) * G;
        conv1_mfma<<<grid, 256, 0, stream>>>(
            disp, normal, left, right, wb1, g1, b1, m1, v1, x1s,
            b0, y_x1_0, rows_x1);
      }
      {
        // conv2 32 -> 64 (MFMA f16, f16 octet in/out, A-prefetch)
        int grid = tilesX * ((rows_x2 + 7) / 8) * G;
        conv3x3_mfma<32, 64, true, 1, 4><<<grid, 256, 0, stream>>>(
            x1s, wb2, g2, b2, m2, v2, (void*)x2s,
            y_x1_0, rows_x1, y_x2_0, rows_x2);
      }
      {
        // conv3 64 -> 24 (MFMA f16, f16 octet in, f16 planar out, A-prefetch)
        int grid = tilesX * ((rows_out + 7) / 8) * G;
        conv3x3_mfma<64, 24, false, 2, 4><<<grid, 256, 0, stream>>>(
            x2s, wb3, nullptr, nullptr, nullptr, nullptr, (void*)oa_buf,
            y_x2_0, rows_x2, y0, rows_out);
      }
      {
        int n = G * rows_out * W_;
        final_band<<<(n + 255) / 256, 256, 0, stream>>>(
            oa_buf, conf, disp, asc, out, b0, G, y0, rows_out);
      }
    }
  }
}

// Round 13
// 560.667 us; speedup vs baseline: 1.1315x; 1.0263x over previous
//
#include <hip/hip_runtime.h>
#include <math.h>

// Problem constants: B=4, H=384, W=1280, NUM=8, IDX_REF=4
static constexpr int B_ = 4;
static constexpr int H_ = 384;
static constexpr int W_ = 1280;
static constexpr int HW_ = H_ * W_;

typedef _Float16 f16x8 __attribute__((ext_vector_type(8)));
typedef float f32x4 __attribute__((ext_vector_type(4)));

// ---------------------------------------------------------------------------
// R13: final_band FUSED into conv3. final reads oa only at its own pixel, so
// conv3's 32x8 block holds everything: after the K-loop the accumulators are
// scattered into the dead stage-LDS as oa_lds[24][8][32] f32 (co-stride 260
// for bank spread), and each thread then runs the propagation epilogue for
// one pixel, writing `out` directly. Kills the final_band dispatch + the
// 94 MB oa round-trip, and oa returns to f32 fidelity (better than R12's
// f16 oa). conv1/conv2 unchanged from R12 (f16 MFMA, fused guidance,
// A-prefetch, G=4/BH=384).
// ---------------------------------------------------------------------------

// ---------------------------------------------------------------------------
// prep_w (conv2/conv3): A-fragment-layout f16 tiles (single plane):
//   wb[(t*CICH+c)*9+s][row16][k32].
// ---------------------------------------------------------------------------
template <int C_IN, int C_OUT>
__global__ __launch_bounds__(256) void prep_w(const float* __restrict__ w,
                                              unsigned short* __restrict__ wb)
{
  constexpr int CICH = C_IN / 32;
  constexpr int NCOT = (C_OUT + 15) / 16;
  constexpr int NE = NCOT * CICH * 9 * 512;
  int i = blockIdx.x * 256 + threadIdx.x;
  if (i >= NE) return;
  int k   = i & 31;
  int row = (i >> 5) & 15;
  int ts  = i >> 9;
  int s   = ts % 9;
  int tc  = ts / 9;
  int c   = tc % CICH;
  int t   = tc / CICH;
  int co  = t * 16 + row;
  int ci  = c * 32 + k;
  float v = 0.f;
  if (co < C_OUT) v = w[((size_t)co * C_IN + ci) * 9 + s];
  union { _Float16 f; unsigned short u; } ch;
  ch.f = (_Float16)v;
  wb[i] = ch.u;
}

// ---------------------------------------------------------------------------
// prep_w1 (conv1 12->32): chunk = ky*2 + kc; kc=0: k = kx*16 + ci (kx 0,1);
// kc=1: k<16 -> kx=2, ci=k; else zero. ci >= 12 -> zero.
// ---------------------------------------------------------------------------
__global__ __launch_bounds__(256) void prep_w1(const float* __restrict__ w,
                                               unsigned short* __restrict__ wb)
{
  constexpr int NE = 2 * 6 * 512;
  int i = blockIdx.x * 256 + threadIdx.x;
  if (i >= NE) return;
  int k    = i & 31;
  int row  = (i >> 5) & 15;
  int ts   = i >> 9;
  int chunk = ts % 6;
  int tc   = ts / 6;
  int ky   = chunk >> 1;
  int kc   = chunk & 1;
  int kx, ci;
  bool valid;
  if (kc == 0) { kx = k >> 4;  ci = k & 15; valid = (ci < 12); }
  else         { kx = 2;       ci = k & 15; valid = (k < 16) && (ci < 12); }
  int co = tc * 16 + row;
  float v = valid ? w[((size_t)co * 12 + ci) * 9 + ky * 3 + kx] : 0.f;
  union { _Float16 f; unsigned short u; } ch;
  ch.f = (_Float16)v;
  wb[i] = ch.u;
}

// ---------------------------------------------------------------------------
// conv1 MFMA (12->32) with guidance fused into the stage.
// LDS [10][36][16 f16] = 11.5 KB; 48 MFMAs/wave.
// ---------------------------------------------------------------------------
__global__ __launch_bounds__(256, 4) void conv1_mfma(
    const float* __restrict__ disp, const float* __restrict__ normal,
    const float* __restrict__ left, const float* __restrict__ right,
    const unsigned short* __restrict__ wb,
    const float* __restrict__ bn_g, const float* __restrict__ bn_b,
    const float* __restrict__ bn_m, const float* __restrict__ bn_v,
    unsigned short* __restrict__ out,   // f16 octet records (x1s)
    int b0, int out_y0, int out_rows)
{
  constexpr int NCOT = 2;
  constexpr int TY  = 8;
  constexpr int HR  = 10;
  constexpr int TXI = 36;

  __shared__ unsigned short smem[HR * TXI * 16];  // 11520 B

  const int tilesX = W_ / 32;
  int bb = blockIdx.x;
  const int txi = bb % tilesX; bb /= tilesX;
  const int tilesY = (out_rows + TY - 1) / TY;
  const int tyi = bb % tilesY;
  const int gi  = bb / tilesY;
  const int b   = b0 + gi;
  const int x0  = txi * 32;
  const int oy0 = out_y0 + tyi * TY;   // global row coords

  const int tid    = threadIdx.x;
  const int w      = tid >> 6;
  const int lane15 = tid & 15;
  const int kgrp   = (tid >> 4) & 3;
  const int aoff   = lane15 * 32 + kgrp * 8;

  f32x4 acc[NCOT][2][2];
#pragma unroll
  for (int i = 0; i < NCOT; i++)
#pragma unroll
    for (int rr = 0; rr < 2; rr++) {
      acc[i][rr][0] = (f32x4){0.f, 0.f, 0.f, 0.f};
      acc[i][rr][1] = (f32x4){0.f, 0.f, 0.f, 0.f};
    }

  // ---- stage: 360 px; compute guidance in-register, pack 16 f16 ----
  for (int it = tid; it < HR * TXI; it += 256) {
    int row = it / TXI;
    int px  = it - row * TXI;
    int gy  = oy0 - 1 + row;
    int gx  = x0 - 2 + px;
    union { _Float16 f[16]; uint4 u[2]; } R;
    R.u[0] = (uint4){0, 0, 0, 0};
    R.u[1] = (uint4){0, 0, 0, 0};
    if (((unsigned)gy < (unsigned)H_) & ((unsigned)gx < (unsigned)W_)) {
      size_t p = (size_t)gy * W_ + gx;
      float d = disp[(size_t)b * HW_ + p];
      float xs = (float)gx - d;
      float x0f = floorf(xs);
      int xi0 = (int)x0f;
      float w1 = xs - x0f;
      int xi1 = xi0 + 1;
      float v0 = (xi0 >= 0 && xi0 < W_) ? 1.f : 0.f;
      float v1 = (xi1 >= 0 && xi1 < W_) ? 1.f : 0.f;
      int xc0 = min(max(xi0, 0), W_ - 1);
      int xc1 = min(max(xi1, 0), W_ - 1);
      float w0f = (1.f - w1) * v0;
      float w1f = w1 * v1;
#pragma unroll
      for (int c = 0; c < 3; c++) {
        const float* rrow = right + (size_t)(b * 3 + c) * HW_ + (size_t)gy * W_;
        float l = left[(size_t)(b * 3 + c) * HW_ + p];
        float n = normal[(size_t)(b * 3 + c) * HW_ + p];
        float r = rrow[gx];
        float warped = w0f * rrow[xc0] + w1f * rrow[xc1];
        R.f[c]     = (_Float16)n;
        R.f[3 + c] = (_Float16)l;
        R.f[6 + c] = (_Float16)r;
        R.f[9 + c] = (_Float16)(warped - l);
      }
    }
    unsigned short* dst = &smem[it * 16];
    *(uint4*)(dst)     = R.u[0];
    *(uint4*)(dst + 8) = R.u[1];
  }
  __syncthreads();

  // ---- K loop: 6 chunks (ky x {kx01, kx2}), A prefetched one chunk ahead ----
  f16x8 ah[NCOT];
#pragma unroll
  for (int tc = 0; tc < NCOT; tc++)
    ah[tc] = *(const f16x8*)(wb + ((size_t)(tc * 6 + 0) * 512 + aoff));
#pragma unroll
  for (int c = 0; c < 6; c++) {
    const int ky = c >> 1, kc = c & 1;
    f16x8 ahn[NCOT];
    if (c < 5) {
#pragma unroll
      for (int tc = 0; tc < NCOT; tc++)
        ahn[tc] = *(const f16x8*)(wb + ((size_t)(tc * 6 + c + 1) * 512 + aoff));
    }
#pragma unroll
    for (int rr = 0; rr < 2; rr++) {
      const int col = (kc ? 3 : 1) + lane15;
      const int e0 = ((2 * w + rr + ky) * TXI + col) * 16 + kgrp * 8;
      f16x8 b0 = *(const f16x8*)&smem[e0];
      f16x8 b1 = *(const f16x8*)&smem[e0 + 256];   // +16 px
#pragma unroll
      for (int tc = 0; tc < NCOT; tc++) {
        acc[tc][rr][0] = __builtin_amdgcn_mfma_f32_16x16x32_f16(
            ah[tc], b0, acc[tc][rr][0], 0, 0, 0);
        acc[tc][rr][1] = __builtin_amdgcn_mfma_f32_16x16x32_f16(
            ah[tc], b1, acc[tc][rr][1], 0, 0, 0);
      }
    }
    if (c < 5) {
#pragma unroll
      for (int tc = 0; tc < NCOT; tc++) ah[tc] = ahn[tc];
    }
  }

  // ---- epilogue: BN+ReLU, f16 octet records ----
#pragma unroll
  for (int rr = 0; rr < 2; rr++) {
    const int orow = oy0 + 2 * w + rr;
    if (orow < out_y0 + out_rows) {
      const int ox = x0 + lane15;
#pragma unroll
      for (int tc = 0; tc < NCOT; tc++) {
        const int o = tc * 2 + (kgrp >> 1);
        const size_t recbase =
            (((size_t)(gi * 4 + o) * out_rows + (orow - out_y0)) * W_ + ox) * 8
            + (kgrp & 1) * 4;
#pragma unroll
        for (int nt = 0; nt < 2; nt++) {
          union { _Float16 f[4]; uint2 u; } Hh;
#pragma unroll
          for (int j = 0; j < 4; j++) {
            const int co = tc * 16 + kgrp * 4 + j;
            float s = bn_g[co] * rsqrtf(bn_v[co] + 1e-5f);
            float v = fmaxf(acc[tc][rr][nt][j] * s + (bn_b[co] - bn_m[co] * s), 0.f);
            Hh.f[j] = (_Float16)v;
          }
          *(uint2*)&out[recbase + (size_t)nt * 128] = Hh.u;
        }
      }
    }
  }
}

// ---------------------------------------------------------------------------
// conv2 MFMA (32->64): plain f16 A and B, A-prefetch, f16 octet records out.
// LDS: 10 x 36 x 36 f16 = 25.9 KB.
// ---------------------------------------------------------------------------
__global__ __launch_bounds__(256, 4) void conv2_mfma(
    const unsigned short* __restrict__ in, const unsigned short* __restrict__ wb,
    const float* __restrict__ bn_g, const float* __restrict__ bn_b,
    const float* __restrict__ bn_m, const float* __restrict__ bn_v,
    unsigned short* __restrict__ out,
    int in_y0, int in_rows, int out_y0, int out_rows)
{
  constexpr int C_IN = 32, C_OUT = 64;
  constexpr int CICH = 1;
  constexpr int NCIO = 4;
  constexpr int NCOT = 4;
  constexpr int TY  = 8;
  constexpr int HR  = 10;
  constexpr int TXI = 36;
  constexpr int PX2 = 18;
  constexpr int PXW = 36;

  __shared__ unsigned short smem[HR * TXI * PXW];  // 25920 B

  const int tilesX = W_ / 32;
  int bb = blockIdx.x;
  const int txi = bb % tilesX; bb /= tilesX;
  const int tilesY = (out_rows + TY - 1) / TY;
  const int tyi = bb % tilesY;
  const int gi  = bb / tilesY;
  const int x0  = txi * 32;
  const int oy0 = out_y0 + tyi * TY;

  const int tid    = threadIdx.x;
  const int w      = tid >> 6;
  const int lane15 = tid & 15;
  const int kgrp   = (tid >> 4) & 3;
  const int aoff   = lane15 * 32 + kgrp * 8;

  f32x4 acc[NCOT][2][2];
#pragma unroll
  for (int i = 0; i < NCOT; i++)
#pragma unroll
    for (int rr = 0; rr < 2; rr++) {
      acc[i][rr][0] = (f32x4){0.f, 0.f, 0.f, 0.f};
      acc[i][rr][1] = (f32x4){0.f, 0.f, 0.f, 0.f};
    }

  for (int it = tid; it < 4 * HR * PX2; it += 256) {   // 720 items
    int cib = it / (HR * PX2);
    int pos = it - cib * (HR * PX2);
    int row = pos / PX2;
    int p2  = pos - row * PX2;
    int gy  = oy0 - 1 + row;
    int by  = gy - in_y0;
    int gx  = x0 - 2 + 2 * p2;
    const bool rok = (unsigned)by < (unsigned)in_rows;
    uint4 h0 = {0,0,0,0}, h1 = {0,0,0,0};
    const unsigned short* src =
        in + (((size_t)(gi * NCIO + cib) * in_rows + by) * W_ + gx) * 8;
    if (rok & ((unsigned)gx < (unsigned)W_))       h0 = *(const uint4*)(src);
    if (rok & ((unsigned)(gx + 1) < (unsigned)W_)) h1 = *(const uint4*)(src + 8);
    int base = (row * TXI + 2 * p2) * PXW + cib * 8;
    *(uint4*)&smem[base]       = h0;
    *(uint4*)&smem[base + PXW] = h1;
  }
  __syncthreads();

  // ---- K loop: 9 taps; A prefetched one tap ahead ----
  f16x8 ah[NCOT];
#pragma unroll
  for (int tc = 0; tc < NCOT; tc++)
    ah[tc] = *(const f16x8*)(wb + ((size_t)(tc * 9) * 512 + aoff));
#pragma unroll
  for (int s = 0; s < 9; s++) {
    const int ky = s / 3, kx = s - 3 * ky;
    f16x8 ahn[NCOT];
    if (s < 8) {
#pragma unroll
      for (int tc = 0; tc < NCOT; tc++)
        ahn[tc] = *(const f16x8*)(wb + ((size_t)(tc * 9 + s + 1) * 512 + aoff));
    }
#pragma unroll
    for (int rr = 0; rr < 2; rr++) {
      const int e0 = ((2 * w + rr + ky) * TXI + 1 + lane15 + kx) * PXW + kgrp * 8;
      f16x8 b0 = *(const f16x8*)&smem[e0];
      f16x8 b1 = *(const f16x8*)&smem[e0 + 16 * PXW];
#pragma unroll
      for (int tc = 0; tc < NCOT; tc++) {
        acc[tc][rr][0] = __builtin_amdgcn_mfma_f32_16x16x32_f16(
            ah[tc], b0, acc[tc][rr][0], 0, 0, 0);
        acc[tc][rr][1] = __builtin_amdgcn_mfma_f32_16x16x32_f16(
            ah[tc], b1, acc[tc][rr][1], 0, 0, 0);
      }
    }
    if (s < 8) {
#pragma unroll
      for (int tc = 0; tc < NCOT; tc++) ah[tc] = ahn[tc];
    }
  }

#pragma unroll
  for (int rr = 0; rr < 2; rr++) {
    const int orow = oy0 + 2 * w + rr;
    if (orow < out_y0 + out_rows) {
      const int ox = x0 + lane15;
#pragma unroll
      for (int tc = 0; tc < NCOT; tc++) {
        const int o = tc * 2 + (kgrp >> 1);
        const size_t recbase =
            (((size_t)(gi * 8 + o) * out_rows + (orow - out_y0)) * W_ + ox) * 8
            + (kgrp & 1) * 4;
#pragma unroll
        for (int nt = 0; nt < 2; nt++) {
          union { _Float16 f[4]; uint2 u; } Hh;
#pragma unroll
          for (int j = 0; j < 4; j++) {
            const int co = tc * 16 + kgrp * 4 + j;
            float s = bn_g[co] * rsqrtf(bn_v[co] + 1e-5f);
            float v = fmaxf(acc[tc][rr][nt][j] * s + (bn_b[co] - bn_m[co] * s), 0.f);
            Hh.f[j] = (_Float16)v;
          }
          *(uint2*)&out[recbase + (size_t)nt * 128] = Hh.u;
        }
      }
    }
  }
}

// ---------------------------------------------------------------------------
// bilinear gather helper (zero-pad semantics)
// ---------------------------------------------------------------------------
__device__ __forceinline__ float bilin1(const float* __restrict__ img,
                                        float ys, float xs)
{
  float y0f = floorf(ys), x0f = floorf(xs);
  int y0 = (int)y0f, x0 = (int)x0f;
  float wy1 = ys - y0f, wx1 = xs - x0f;
  float wy0 = 1.f - wy1, wx0 = 1.f - wx1;
  int y1 = y0 + 1, x1 = x0 + 1;
  float vy0 = (y0 >= 0 && y0 < H_) ? 1.f : 0.f;
  float vy1 = (y1 >= 0 && y1 < H_) ? 1.f : 0.f;
  float vx0 = (x0 >= 0 && x0 < W_) ? 1.f : 0.f;
  float vx1 = (x1 >= 0 && x1 < W_) ? 1.f : 0.f;
  int yc0 = min(max(y0, 0), H_ - 1), yc1 = min(max(y1, 0), H_ - 1);
  int xc0 = min(max(x0, 0), W_ - 1), xc1 = min(max(x1, 0), W_ - 1);
  const float* r0 = img + (size_t)yc0 * W_;
  const float* r1 = img + (size_t)yc1 * W_;
  float v00 = r0[xc0], v01 = r0[xc1], v10 = r1[xc0], v11 = r1[xc1];
  return (wy0 * vy0) * ((wx0 * vx0) * v00 + (wx1 * vx1) * v01) +
         (wy1 * vy1) * ((wx0 * vx0) * v10 + (wx1 * vx1) * v11);
}

// ---------------------------------------------------------------------------
// conv3 (64->24) + final propagation FUSED. After the K-loop the 24-channel
// oa tile lives in the block's accumulators; scatter to LDS (f32,
// [24][8][32], co-stride 260 for bank spread) and each thread finishes one
// pixel: conf/disp bilinear gathers, tanh, normalization, blend, store.
// ---------------------------------------------------------------------------
__global__ __launch_bounds__(256, 4) void conv3_final(
    const unsigned short* __restrict__ in, const unsigned short* __restrict__ wb,
    const float* __restrict__ conf, const float* __restrict__ disp,
    const float* __restrict__ asc, float* __restrict__ outp,
    int b0, int in_y0, int in_rows, int out_y0, int out_rows)
{
  constexpr int NCIO = 8;   // input octets (C_IN=64)
  constexpr int CICH = 2;
  constexpr int NCOT = 2;   // co tiles (C_OUT=24 -> 2 tiles of 16)
  constexpr int TY  = 8;
  constexpr int HR  = 10;
  constexpr int TXI = 36;
  constexpr int PX2 = 18;
  constexpr int PXW = 36;
  constexpr int COS = 260;  // oa_lds co stride (floats); 24*260*4 = 24960 B

  __shared__ unsigned short smem[HR * TXI * PXW];  // 25920 B (>= 24960)
  float* oal = (float*)smem;

  const int tilesX = W_ / 32;
  int bb = blockIdx.x;
  const int txi = bb % tilesX; bb /= tilesX;
  const int tilesY = (out_rows + TY - 1) / TY;
  const int tyi = bb % tilesY;
  const int gi  = bb / tilesY;
  const int b   = b0 + gi;
  const int x0  = txi * 32;
  const int oy0 = out_y0 + tyi * TY;

  const int tid    = threadIdx.x;
  const int w      = tid >> 6;
  const int lane15 = tid & 15;
  const int kgrp   = (tid >> 4) & 3;
  const int aoff   = lane15 * 32 + kgrp * 8;

  f32x4 acc[NCOT][2][2];
#pragma unroll
  for (int i = 0; i < NCOT; i++)
#pragma unroll
    for (int rr = 0; rr < 2; rr++) {
      acc[i][rr][0] = (f32x4){0.f, 0.f, 0.f, 0.f};
      acc[i][rr][1] = (f32x4){0.f, 0.f, 0.f, 0.f};
    }

  for (int cc = 0; cc < CICH; ++cc) {
    if (cc) __syncthreads();
    for (int it = tid; it < 4 * HR * PX2; it += 256) {
      int cib = it / (HR * PX2);
      int pos = it - cib * (HR * PX2);
      int row = pos / PX2;
      int p2  = pos - row * PX2;
      int gy  = oy0 - 1 + row;
      int by  = gy - in_y0;
      int gx  = x0 - 2 + 2 * p2;
      const bool rok = (unsigned)by < (unsigned)in_rows;
      uint4 h0 = {0,0,0,0}, h1 = {0,0,0,0};
      const unsigned short* src =
          in + (((size_t)(gi * NCIO + cc * 4 + cib) * in_rows + by) * W_ + gx) * 8;
      if (rok & ((unsigned)gx < (unsigned)W_))       h0 = *(const uint4*)(src);
      if (rok & ((unsigned)(gx + 1) < (unsigned)W_)) h1 = *(const uint4*)(src + 8);
      int base = (row * TXI + 2 * p2) * PXW + cib * 8;
      *(uint4*)&smem[base]       = h0;
      *(uint4*)&smem[base + PXW] = h1;
    }
    __syncthreads();

    f16x8 ah[NCOT];
#pragma unroll
    for (int tc = 0; tc < NCOT; tc++)
      ah[tc] = *(const f16x8*)(
          wb + ((size_t)((tc * CICH + cc) * 9) * 512 + aoff));
#pragma unroll
    for (int s = 0; s < 9; s++) {
      const int ky = s / 3, kx = s - 3 * ky;
      f16x8 ahn[NCOT];
      if (s < 8) {
#pragma unroll
        for (int tc = 0; tc < NCOT; tc++)
          ahn[tc] = *(const f16x8*)(
              wb + ((size_t)((tc * CICH + cc) * 9 + s + 1) * 512 + aoff));
      }
#pragma unroll
      for (int rr = 0; rr < 2; rr++) {
        const int e0 = ((2 * w + rr + ky) * TXI + 1 + lane15 + kx) * PXW + kgrp * 8;
        f16x8 b0 = *(const f16x8*)&smem[e0];
        f16x8 b1 = *(const f16x8*)&smem[e0 + 16 * PXW];
#pragma unroll
        for (int tc = 0; tc < NCOT; tc++) {
          acc[tc][rr][0] = __builtin_amdgcn_mfma_f32_16x16x32_f16(
              ah[tc], b0, acc[tc][rr][0], 0, 0, 0);
          acc[tc][rr][1] = __builtin_amdgcn_mfma_f32_16x16x32_f16(
              ah[tc], b1, acc[tc][rr][1], 0, 0, 0);
        }
      }
      if (s < 8) {
#pragma unroll
        for (int tc = 0; tc < NCOT; tc++) ah[tc] = ahn[tc];
      }
    }
  }

  // ---- scatter oa tile to LDS (stage buffer is dead) ----
  __syncthreads();
#pragma unroll
  for (int tc = 0; tc < NCOT; tc++) {
#pragma unroll
    for (int j = 0; j < 4; j++) {
      const int co = tc * 16 + kgrp * 4 + j;
      if (co < 24) {
#pragma unroll
        for (int rr = 0; rr < 2; rr++) {
          const int row = 2 * w + rr;
#pragma unroll
          for (int nt = 0; nt < 2; nt++)
            oal[co * COS + row * 32 + lane15 + nt * 16] = acc[tc][rr][nt][j];
        }
      }
    }
  }
  __syncthreads();

  // ---- final propagation: one pixel per thread ----
  const int px = tid & 31;
  const int r  = tid >> 5;
  const int orow = oy0 + r;
  const int gx = x0 + px;
  if (orow < out_y0 + out_rows) {
    const float scale = 1.f / (asc[0] + 1e-8f);
    const float* cimg = conf + (size_t)b * HW_;
    const float* dimg = disp + (size_t)b * HW_;
    const int base = r * 32 + px;

    float offy[8], offx[8], a[8];
#pragma unroll
    for (int k = 0; k < 8; k++) {
      offy[k] = oal[(size_t)k * COS + base];
      offx[k] = oal[(size_t)(8 + k) * COS + base];
      float ar = oal[(size_t)(16 + k) * COS + base];
      float ca = bilin1(cimg, (float)orow + offy[k], (float)gx + offx[k]);
      a[k] = tanhf(ar) * scale * ca;
    }

    float s = 1e-4f;
#pragma unroll
    for (int k = 0; k < 8; k++) s += fabsf(a[k]);
    s = fmaxf(s, 1.f);
    float inv = 1.f / s;
    float suma = 0.f;
#pragma unroll
    for (int k = 0; k < 8; k++) { a[k] *= inv; suma += a[k]; }
    float aref = 1.f - suma;

    float inter = 0.f;
#pragma unroll
    for (int k9 = 0; k9 < 9; k9++) {
      float oy, ox, wk;
      if (k9 < 4)       { oy = offy[k9];     ox = offx[k9];     wk = a[k9]; }
      else if (k9 == 4) { oy = 0.f;          ox = 0.f;          wk = aref;  }
      else              { oy = offy[k9 - 1]; ox = offx[k9 - 1]; wk = a[k9 - 1]; }
      float ky = (float)(k9 / 3) - 1.f;
      float kx = (float)(k9 % 3) - 1.f;
      inter += wk * bilin1(dimg, (float)orow + ky + oy, (float)gx + kx + ox);
    }
    inter = fmaxf(inter, 0.f);
    float cd = dimg[(size_t)orow * W_ + gx];
    outp[(size_t)b * HW_ + (size_t)orow * W_ + gx] =
        fmaxf(0.7f * cd + 0.3f * inter, 0.f);
  }
}

// ---------------------------------------------------------------------------
extern "C" void kernel_launch(void* const* d_in, const int* in_sizes, int n_in,
                              void* d_out, int out_size, void* d_ws, size_t ws_size,
                              hipStream_t stream)
{
  const float* disp   = (const float*)d_in[0];
  const float* normal = (const float*)d_in[1];
  const float* left   = (const float*)d_in[2];
  const float* right  = (const float*)d_in[3];
  const float* conf   = (const float*)d_in[4];
  const float* w1     = (const float*)d_in[5];
  const float* g1     = (const float*)d_in[6];
  const float* b1     = (const float*)d_in[7];
  const float* m1     = (const float*)d_in[8];
  const float* v1     = (const float*)d_in[9];
  const float* w2     = (const float*)d_in[10];
  const float* g2     = (const float*)d_in[11];
  const float* b2     = (const float*)d_in[12];
  const float* m2     = (const float*)d_in[13];
  const float* v2     = (const float*)d_in[14];
  const float* w3     = (const float*)d_in[15];
  const float* asc    = (const float*)d_in[16];
  float* out = (float*)d_out;

  constexpr int WB1E = 2 * 6 * 512;      // 6144 ushorts
  constexpr int WB2E = 4 * 1 * 9 * 512;  // 18432
  constexpr int WB3E = 2 * 2 * 9 * 512;  // 18432
  const size_t wbytes = (size_t)(WB1E + WB2E + WB3E) * sizeof(unsigned short);

  // Band buffers (bytes/px-col): x1s 64*(bh+4), x2s 128*(bh+2). No oa buffer.
  struct Cfg { int g, bh; };
  const Cfg cfgs[] = {{4, 384}, {2, 384}, {1, 384}, {4, 96}, {2, 96},
                      {1, 96}, {1, 48}, {1, 24}, {1, 12}, {1, 8}, {1, 4}};
  int G = 1, BH = 4;
  for (const Cfg& c : cfgs) {
    size_t bytes = (size_t)c.g * W_ *
                   (64u * (c.bh + 4) + 128u * (c.bh + 2));
    if (bytes + wbytes <= ws_size) { G = c.g; BH = c.bh; break; }
  }

  unsigned short* x1s = (unsigned short*)d_ws;
  unsigned short* x2s = x1s + (size_t)G * 32 * (BH + 4) * W_;
  unsigned short* wb1 = x2s + (size_t)G * 64 * (BH + 2) * W_;
  unsigned short* wb2 = wb1 + WB1E;
  unsigned short* wb3 = wb2 + WB2E;

  prep_w1<<<(WB1E + 255) / 256, 256, 0, stream>>>(w1, wb1);
  prep_w<32, 64><<<(WB2E + 255) / 256, 256, 0, stream>>>(w2, wb2);
  prep_w<64, 24><<<(WB3E + 255) / 256, 256, 0, stream>>>(w3, wb3);

  const int tilesX = W_ / 32;

  for (int b0 = 0; b0 < B_; b0 += G) {
    for (int y0 = 0; y0 < H_; y0 += BH) {
      const int rows_out = min(BH, H_ - y0);
      const int y_x2_0 = max(y0 - 1, 0);
      const int y_x2_1 = min(y0 + rows_out + 1, H_);
      const int rows_x2 = y_x2_1 - y_x2_0;
      const int y_x1_0 = max(y0 - 2, 0);
      const int y_x1_1 = min(y0 + rows_out + 2, H_);
      const int rows_x1 = y_x1_1 - y_x1_0;

      {
        // conv1 12 -> 32 (MFMA, guidance fused, f16 out)
        int grid = tilesX * ((rows_x1 + 7) / 8) * G;
        conv1_mfma<<<grid, 256, 0, stream>>>(
            disp, normal, left, right, wb1, g1, b1, m1, v1, x1s,
            b0, y_x1_0, rows_x1);
      }
      {
        // conv2 32 -> 64 (MFMA f16, octet in/out, A-prefetch)
        int grid = tilesX * ((rows_x2 + 7) / 8) * G;
        conv2_mfma<<<grid, 256, 0, stream>>>(
            x1s, wb2, g2, b2, m2, v2, x2s,
            y_x1_0, rows_x1, y_x2_0, rows_x2);
      }
      {
        // conv3 64 -> 24 + final propagation (fused; f32 oa via LDS)
        int grid = tilesX * ((rows_out + 7) / 8) * G;
        conv3_final<<<grid, 256, 0, stream>>>(
            x2s, wb3, conf, disp, asc, out,
            b0, y_x2_0, rows_x2, y0, rows_out);
      }
    }
  }
}